// Round 1
// baseline (134.675 us; speedup 1.0000x reference)
//
#include <hip/hip_runtime.h>

// out[i] = sum_{j=0..9} in[10*i + j] * (j+1)/55   (stride==d==10, windows tile T exactly)
// Each thread handles 2 windows = 20 contiguous floats = 5 aligned float4 loads.

__global__ __launch_bounds__(256) void ts_decaylinear_kernel(
    const float* __restrict__ in, float* __restrict__ out, long long n_pairs) {

    const float w0 = 1.0f / 55.0f, w1 = 2.0f / 55.0f, w2 = 3.0f / 55.0f,
                w3 = 4.0f / 55.0f, w4 = 5.0f / 55.0f, w5 = 6.0f / 55.0f,
                w6 = 7.0f / 55.0f, w7 = 8.0f / 55.0f, w8 = 9.0f / 55.0f,
                w9 = 10.0f / 55.0f;

    long long idx    = (long long)blockIdx.x * blockDim.x + threadIdx.x;
    long long gs     = (long long)gridDim.x * blockDim.x;

    for (; idx < n_pairs; idx += gs) {
        const float4* p = reinterpret_cast<const float4*>(in) + idx * 5;
        float4 a0 = p[0];
        float4 a1 = p[1];
        float4 a2 = p[2];
        float4 a3 = p[3];
        float4 a4 = p[4];

        float s0 = a0.x * w0 + a0.y * w1 + a0.z * w2 + a0.w * w3
                 + a1.x * w4 + a1.y * w5 + a1.z * w6 + a1.w * w7
                 + a2.x * w8 + a2.y * w9;

        float s1 = a2.z * w0 + a2.w * w1
                 + a3.x * w2 + a3.y * w3 + a3.z * w4 + a3.w * w5
                 + a4.x * w6 + a4.y * w7 + a4.z * w8 + a4.w * w9;

        reinterpret_cast<float2*>(out)[idx] = make_float2(s0, s1);
    }
}

extern "C" void kernel_launch(void* const* d_in, const int* in_sizes, int n_in,
                              void* d_out, int out_size, void* d_ws, size_t ws_size,
                              hipStream_t stream) {
    const float* in = (const float*)d_in[0];
    float* out = (float*)d_out;

    // out_size = B*n*w = 15,360,000 ; each thread computes 2 outputs.
    long long n_pairs = (long long)out_size / 2;

    int block = 256;
    long long blocks_needed = (n_pairs + block - 1) / block;
    int grid = (int)(blocks_needed < 2048 ? blocks_needed : 2048);

    ts_decaylinear_kernel<<<grid, block, 0, stream>>>(in, out, n_pairs);
}